// Round 5
// baseline (72.886 us; speedup 1.0000x reference)
//
#include <hip/hip_runtime.h>

#define KLD_EPS 1e-6f

// Fused single-kernel GazeKLD.
// - Per tile (256 rows x 32 floats = 32 KiB): async global_load_lds staging,
//   linear LDS dest + inverse-XOR-swizzled global source + swizzled read.
// - Wave-private pipeline: wave wid stages LDS float4s j = i*256+wid*64+lane,
//   i.e. exactly rows r with (r>>3)&3 == wid. Each wave computes only the rows
//   it staged (lane l -> row (l>>3)*32 + wid*8 + (l&7)), so a per-wave
//   s_waitcnt vmcnt(0) replaces __syncthreads() -- no in-loop barriers at all,
//   waves de-phase and keep HBM demand continuous.
// - Stage-2 fused via last-block ticket (counter memset to 0 each launch);
//   last block sums partials in fixed order -> deterministic.
__global__ __launch_bounds__(256) void gaze_kld_fused(
    const float* __restrict__ pred,
    const float* __restrict__ tru,
    float* __restrict__ out,
    float* __restrict__ partials,
    int* __restrict__ counter,
    int B, int nTiles, int nBlocks)
{
    __shared__ float4 lds4[2048];   // 32 KiB
    __shared__ float sm[4];
    __shared__ int lastFlag;

    const int t    = threadIdx.x;
    const int lane = t & 63;
    const int wid  = t >> 6;

    const float4* __restrict__ tru4  = (const float4*)tru;   // 8 float4 per row
    const float4* __restrict__ pred4 = (const float4*)pred;  // 1 float4 per row

    // row within tile owned by this lane == a row this wave's DMA staged
    const int rowL = ((lane >> 3) << 5) + (wid << 3) + (lane & 7);
    const int swz  = rowL & 7;      // == lane & 7

    float local = 0.0f;

    for (int tb = blockIdx.x; tb < nTiles; tb += gridDim.x) {
        const int row = tb * 256 + rowL;
        float sx = 0.f, sy = 0.f, sxx = 0.f, syy = 0.f;
        float4 p;

        if (tb * 256 + 256 <= B) {
            // ---- full tile: DMA stage own rows, wave-private wait ----
            p = pred4[row];
            const long long gBase = (long long)tb * 2048;
            #pragma unroll
            for (int i = 0; i < 8; ++i) {
                int j   = i * 256 + wid * 64 + lane;
                int src = (j & ~7) | ((j & 7) ^ ((j >> 3) & 7));
                __builtin_amdgcn_global_load_lds(
                    (const __attribute__((address_space(1))) void*)(tru4 + gBase + src),
                    (__attribute__((address_space(3))) void*)&lds4[i * 256 + wid * 64],
                    16, 0, 0);
            }
            asm volatile("s_waitcnt vmcnt(0)" ::: "memory");
            __builtin_amdgcn_sched_barrier(0);

            #pragma unroll
            for (int k = 0; k < 8; ++k) {
                float4 v = lds4[rowL * 8 + (k ^ swz)];
                sx  += v.x + v.z;
                sy  += v.y + v.w;
                sxx += v.x * v.x + v.z * v.z;
                syy += v.y * v.y + v.w * v.w;
            }
        } else {
            // ---- tail tile (unused when B % 256 == 0): direct guarded loads ----
            p = make_float4(0.f, 0.f, 1.f, 1.f);
            if (row < B) {
                p = pred4[row];
                const float4* r4 = tru4 + (long long)row * 8;
                #pragma unroll
                for (int k = 0; k < 8; ++k) {
                    float4 v = r4[k];
                    sx  += v.x + v.z;
                    sy  += v.y + v.w;
                    sxx += v.x * v.x + v.z * v.z;
                    syy += v.y * v.y + v.w * v.w;
                }
            }
        }

        if (row < B) {
            float pmx = p.x, pmy = p.y;
            float pvx = p.z + KLD_EPS, pvy = p.w + KLD_EPS;

            float tmx = sx * (1.0f / 16.0f);
            float tmy = sy * (1.0f / 16.0f);
            float tvx = (sxx - 16.0f * tmx * tmx) * (1.0f / 15.0f) + KLD_EPS;
            float tvy = (syy - 16.0f * tmy * tmy) * (1.0f / 15.0f) + KLD_EPS;

            float dx = pmx - tmx, dy = pmy - tmy;
            local += 0.5f * ( __logf(pvx / tvx) + tvx / pvx + dx * dx / pvx
                            + __logf(pvy / tvy) + tvy / pvy + dy * dy / pvy
                            - 2.0f );
        }
    }

    // ---- deterministic block reduction ----
    #pragma unroll
    for (int off = 32; off > 0; off >>= 1)
        local += __shfl_down(local, off);
    if ((t & 63) == 0) sm[t >> 6] = local;
    __syncthreads();

    if (t == 0) {
        partials[blockIdx.x] = (sm[0] + sm[1]) + (sm[2] + sm[3]);
        __threadfence();                         // partial visible device-wide
        int ticket = atomicAdd(counter, 1);
        lastFlag = (ticket == nBlocks - 1) ? 1 : 0;
    }
    __syncthreads();

    // ---- last block: fixed-order final reduction ----
    if (lastFlag) {
        __threadfence();                         // acquire all partials
        float s = 0.0f;
        for (int i = t; i < nBlocks; i += 256) s += partials[i];
        __syncthreads();                         // sm reuse safety
        #pragma unroll
        for (int off = 32; off > 0; off >>= 1)
            s += __shfl_down(s, off);
        if ((t & 63) == 0) sm[t >> 6] = s;
        __syncthreads();
        if (t == 0)
            out[0] = ((sm[0] + sm[1]) + (sm[2] + sm[3])) * (1.0f / (float)B);
    }
}

extern "C" void kernel_launch(void* const* d_in, const int* in_sizes, int n_in,
                              void* d_out, int out_size, void* d_ws, size_t ws_size,
                              hipStream_t stream) {
    const float* pred = (const float*)d_in[0];
    const float* tru  = (const float*)d_in[1];
    float* out = (float*)d_out;

    const int B = in_sizes[0] / 4;          // pred is (B,4)
    const int nTiles = (B + 255) / 256;

    int blocks = 1280;                      // 5 blocks/CU (32 KiB LDS each = 160 KiB)
    if (blocks > nTiles) blocks = nTiles;
    // ws layout: [0,4) ticket counter, [1024, 1024+4*blocks) partials
    if (ws_size >= 1024 + sizeof(float)) {
        size_t maxBlocks = (ws_size - 1024) / sizeof(float);
        if ((size_t)blocks > maxBlocks) blocks = (int)maxBlocks;
    } else {
        blocks = 1;
    }
    if (blocks < 1) blocks = 1;

    int*   counter  = (int*)d_ws;
    float* partials = (float*)((char*)d_ws + 1024);

    hipMemsetAsync(d_ws, 0, sizeof(int), stream);   // reset ticket each call
    gaze_kld_fused<<<blocks, 256, 0, stream>>>(pred, tru, out, partials, counter,
                                               B, nTiles, blocks);
}

// Round 6
// 63.537 us; speedup vs baseline: 1.1471x; 1.1471x over previous
//
#include <hip/hip_runtime.h>

#define KLD_EPS 1e-6f

// R3 structure (proven 30.7us) + fused final reduction. Barriers kept.
// Per tile (256 rows x 32 f32 = 32 KiB): global_load_lds staging with
// linear LDS dest + inverse-XOR-swizzled global source + swizzled read
// (XOR is an involution; permutation stays within each row's 128-B line,
// so coalescing is unchanged). Read offset k^(t&7) is bank-conflict-free.
// Ending: last-block ticket (memset to 0 each launch), fixed-order sum.
__global__ __launch_bounds__(256) void gaze_kld_fused(
    const float* __restrict__ pred,
    const float* __restrict__ tru,
    float* __restrict__ out,
    float* __restrict__ partials,
    int* __restrict__ counter,
    int B, int nTiles, int nBlocks)
{
    __shared__ float4 lds4[2048];   // 32 KiB
    __shared__ float sm[4];
    __shared__ int lastFlag;

    const int t    = threadIdx.x;
    const int lane = t & 63;
    const int wid  = t >> 6;

    const float4* __restrict__ tru4  = (const float4*)tru;   // 8 float4 per row
    const float4* __restrict__ pred4 = (const float4*)pred;  // 1 float4 per row

    float local = 0.0f;
    const long long totF4 = (long long)B * 8;

    for (int tb = blockIdx.x; tb < nTiles; tb += gridDim.x) {
        const long long gBase = (long long)tb * 2048;
        const int row = tb * 256 + t;

        // pred for own row: independent, issued alongside staging
        float4 p = make_float4(0.f, 0.f, 1.f, 1.f);
        if (row < B) p = pred4[row];

        if (tb * 256 + 256 <= B) {
            // full tile: async DMA staging, no VGPR round-trip
            #pragma unroll
            for (int i = 0; i < 8; ++i) {
                int j   = i * 256 + wid * 64 + lane;
                int src = (j & ~7) | ((j & 7) ^ ((j >> 3) & 7));
                __builtin_amdgcn_global_load_lds(
                    (const __attribute__((address_space(1))) void*)(tru4 + gBase + src),
                    (__attribute__((address_space(3))) void*)&lds4[i * 256 + wid * 64],
                    16, 0, 0);
            }
        } else {
            // tail tile (unused when B % 256 == 0): VGPR path, swizzled ds_write
            #pragma unroll
            for (int i = 0; i < 8; ++i) {
                int gl = i * 256 + t;
                long long g = gBase + gl;
                float4 v = make_float4(0.f, 0.f, 0.f, 0.f);
                if (g < totF4) v = tru4[g];
                int r = gl >> 3, k = gl & 7;
                lds4[r * 8 + (k ^ (r & 7))] = v;
            }
        }

        __syncthreads();   // drains vmcnt (DMA) + lgkmcnt for whole block

        float sx = 0.f, sy = 0.f, sxx = 0.f, syy = 0.f;
        #pragma unroll
        for (int k = 0; k < 8; ++k) {
            float4 v = lds4[t * 8 + (k ^ (t & 7))];
            sx  += v.x + v.z;
            sy  += v.y + v.w;
            sxx += v.x * v.x + v.z * v.z;
            syy += v.y * v.y + v.w * v.w;
        }

        __syncthreads();   // reads done before next iteration overwrites

        if (row < B) {
            float pmx = p.x, pmy = p.y;
            float pvx = p.z + KLD_EPS, pvy = p.w + KLD_EPS;

            float tmx = sx * (1.0f / 16.0f);
            float tmy = sy * (1.0f / 16.0f);
            float tvx = (sxx - 16.0f * tmx * tmx) * (1.0f / 15.0f) + KLD_EPS;
            float tvy = (syy - 16.0f * tmy * tmy) * (1.0f / 15.0f) + KLD_EPS;

            float dx = pmx - tmx, dy = pmy - tmy;
            local += 0.5f * ( __logf(pvx / tvx) + tvx / pvx + dx * dx / pvx
                            + __logf(pvy / tvy) + tvy / pvy + dy * dy / pvy
                            - 2.0f );
        }
    }

    // deterministic block reduction
    #pragma unroll
    for (int off = 32; off > 0; off >>= 1)
        local += __shfl_down(local, off);
    if ((t & 63) == 0) sm[t >> 6] = local;
    __syncthreads();

    if (t == 0) {
        partials[blockIdx.x] = (sm[0] + sm[1]) + (sm[2] + sm[3]);
        __threadfence();                         // release: partial visible
        int ticket = atomicAdd(counter, 1);
        lastFlag = (ticket == nBlocks - 1) ? 1 : 0;
    }
    __syncthreads();

    // last block: fixed-order final reduction -> deterministic output
    if (lastFlag) {
        __threadfence();                         // acquire all partials
        float s = 0.0f;
        for (int i = t; i < nBlocks; i += 256) s += partials[i];
        __syncthreads();
        #pragma unroll
        for (int off = 32; off > 0; off >>= 1)
            s += __shfl_down(s, off);
        if ((t & 63) == 0) sm[t >> 6] = s;
        __syncthreads();
        if (t == 0)
            out[0] = ((sm[0] + sm[1]) + (sm[2] + sm[3])) * (1.0f / (float)B);
    }
}

extern "C" void kernel_launch(void* const* d_in, const int* in_sizes, int n_in,
                              void* d_out, int out_size, void* d_ws, size_t ws_size,
                              hipStream_t stream) {
    const float* pred = (const float*)d_in[0];
    const float* tru  = (const float*)d_in[1];
    float* out = (float*)d_out;

    const int B = in_sizes[0] / 4;          // pred is (B,4)
    const int nTiles = (B + 255) / 256;

    int blocks = 1024;                      // 4 blocks/CU (proven best)
    if (blocks > nTiles) blocks = nTiles;
    // ws layout: [0,4) ticket counter, [1024, 1024+4*blocks) partials
    if (ws_size >= 1024 + sizeof(float)) {
        size_t maxBlocks = (ws_size - 1024) / sizeof(float);
        if ((size_t)blocks > maxBlocks) blocks = (int)maxBlocks;
    } else {
        blocks = 1;
    }
    if (blocks < 1) blocks = 1;

    int*   counter  = (int*)d_ws;
    float* partials = (float*)((char*)d_ws + 1024);

    hipMemsetAsync(d_ws, 0, sizeof(int), stream);   // reset ticket each launch
    gaze_kld_fused<<<blocks, 256, 0, stream>>>(pred, tru, out, partials, counter,
                                               B, nTiles, blocks);
}

// Round 7
// 33.478 us; speedup vs baseline: 2.1771x; 1.8979x over previous
//
#include <hip/hip_runtime.h>

#define KLD_EPS 1e-6f

// Two-kernel structure (proven). Stage 1: one 256-row tile per block.
// global_load_lds staging: linear LDS dest + inverse-XOR-swizzled global
// source + swizzled read (XOR involution; permutation stays within each
// row's 128-B line so coalescing is unchanged). LDS is exactly 32 KiB
// (reduction scratch folded into lds4) -> 5 blocks/CU, 20 waves/CU.
__global__ __launch_bounds__(256) void gaze_kld_partial(
    const float* __restrict__ pred,
    const float* __restrict__ tru,
    float* __restrict__ partial,
    int B)
{
    __shared__ float4 lds4[2048];   // exactly 32 KiB; reused for block reduce

    const int t    = threadIdx.x;
    const int lane = t & 63;
    const int wid  = t >> 6;
    const int tb   = blockIdx.x;

    const float4* __restrict__ tru4  = (const float4*)tru;   // 8 float4 per row
    const float4* __restrict__ pred4 = (const float4*)pred;  // 1 float4 per row

    const long long gBase = (long long)tb * 2048;
    const int row = tb * 256 + t;
    const long long totF4 = (long long)B * 8;

    // pred for own row: independent, issued alongside staging
    float4 p = make_float4(0.f, 0.f, 1.f, 1.f);
    if (row < B) p = pred4[row];

    if (tb * 256 + 256 <= B) {
        // full tile: async DMA staging, no VGPR round-trip
        #pragma unroll
        for (int i = 0; i < 8; ++i) {
            int j   = i * 256 + wid * 64 + lane;
            int src = (j & ~7) | ((j & 7) ^ ((j >> 3) & 7));
            __builtin_amdgcn_global_load_lds(
                (const __attribute__((address_space(1))) void*)(tru4 + gBase + src),
                (__attribute__((address_space(3))) void*)&lds4[i * 256 + wid * 64],
                16, 0, 0);
        }
    } else {
        // tail tile (unused when B % 256 == 0): VGPR path, swizzled ds_write
        #pragma unroll
        for (int i = 0; i < 8; ++i) {
            int gl = i * 256 + t;
            long long g = gBase + gl;
            float4 v = make_float4(0.f, 0.f, 0.f, 0.f);
            if (g < totF4) v = tru4[g];
            int r = gl >> 3, k = gl & 7;
            lds4[r * 8 + (k ^ (r & 7))] = v;
        }
    }

    __syncthreads();   // drains DMA vmcnt + lgkmcnt for the block

    float sx = 0.f, sy = 0.f, sxx = 0.f, syy = 0.f;
    #pragma unroll
    for (int k = 0; k < 8; ++k) {
        float4 v = lds4[t * 8 + (k ^ (t & 7))];
        sx  += v.x + v.z;
        sy  += v.y + v.w;
        sxx += v.x * v.x + v.z * v.z;
        syy += v.y * v.y + v.w * v.w;
    }

    float local = 0.0f;
    if (row < B) {
        float pmx = p.x, pmy = p.y;
        float pvx = p.z + KLD_EPS, pvy = p.w + KLD_EPS;

        float tmx = sx * (1.0f / 16.0f);
        float tmy = sy * (1.0f / 16.0f);
        float tvx = (sxx - 16.0f * tmx * tmx) * (1.0f / 15.0f) + KLD_EPS;
        float tvy = (syy - 16.0f * tmy * tmy) * (1.0f / 15.0f) + KLD_EPS;

        float dx = pmx - tmx, dy = pmy - tmy;
        local = 0.5f * ( __logf(pvx / tvx) + tvx / pvx + dx * dx / pvx
                       + __logf(pvy / tvy) + tvy / pvy + dy * dy / pvy
                       - 2.0f );
    }

    // deterministic block reduction (scratch folded into lds4)
    #pragma unroll
    for (int off = 32; off > 0; off >>= 1)
        local += __shfl_down(local, off);
    __syncthreads();                         // all lds4 reads complete
    if (lane == 0) ((float*)lds4)[wid] = local;
    __syncthreads();
    if (t == 0) {
        float* smf = (float*)lds4;
        partial[tb] = (smf[0] + smf[1]) + (smf[2] + smf[3]);
    }
}

// Stage 2: single block sums per-block partials in fixed order, scales by 1/B.
__global__ __launch_bounds__(256) void gaze_kld_final(
    const float* __restrict__ partial, int n,
    float* __restrict__ out, float invB)
{
    const int t = threadIdx.x;
    float s = 0.0f;
    for (int i = t; i < n; i += blockDim.x) s += partial[i];

    __shared__ float sm[4];
    #pragma unroll
    for (int off = 32; off > 0; off >>= 1)
        s += __shfl_down(s, off);
    if ((t & 63) == 0) sm[t >> 6] = s;
    __syncthreads();
    if (t == 0)
        out[0] = ((sm[0] + sm[1]) + (sm[2] + sm[3])) * invB;
}

extern "C" void kernel_launch(void* const* d_in, const int* in_sizes, int n_in,
                              void* d_out, int out_size, void* d_ws, size_t ws_size,
                              hipStream_t stream) {
    const float* pred = (const float*)d_in[0];
    const float* tru  = (const float*)d_in[1];
    float* out = (float*)d_out;

    const int B = in_sizes[0] / 4;          // pred is (B,4)
    int nTiles = (B + 255) / 256;           // one tile per block

    size_t maxBlocks = ws_size / sizeof(float);
    if ((size_t)nTiles > maxBlocks) nTiles = (int)maxBlocks;  // safety (not hit here)
    if (nTiles < 1) nTiles = 1;

    float* partials = (float*)d_ws;

    gaze_kld_partial<<<nTiles, 256, 0, stream>>>(pred, tru, partials, B);
    gaze_kld_final<<<1, 256, 0, stream>>>(partials, nTiles, out, 1.0f / (float)B);
}

// Round 8
// 31.296 us; speedup vs baseline: 2.3289x; 1.0697x over previous
//
#include <hip/hip_runtime.h>

#define KLD_EPS 1e-6f

// R4 structure (proven ~30.7us) with LDS trimmed to exactly 32 KiB:
// reduction scratch folded into lds4 -> 5 blocks/CU (20 waves) instead of 4.
// Grid = 1280 blocks (exactly 5/CU co-resident), grid-stride over 4096 tiles.
// Staging: global_load_lds, linear LDS dest + inverse-XOR-swizzled global
// source + swizzled read (XOR involution; permutation stays within each
// row's 128-B line so coalescing is unchanged).
__global__ __launch_bounds__(256) void gaze_kld_partial(
    const float* __restrict__ pred,
    const float* __restrict__ tru,
    float* __restrict__ partial,
    int B, int nTiles)
{
    __shared__ float4 lds4[2048];   // exactly 32 KiB; reused post-loop for reduce

    const int t    = threadIdx.x;
    const int lane = t & 63;
    const int wid  = t >> 6;

    const float4* __restrict__ tru4  = (const float4*)tru;   // 8 float4 per row
    const float4* __restrict__ pred4 = (const float4*)pred;  // 1 float4 per row

    float local = 0.0f;
    const long long totF4 = (long long)B * 8;

    for (int tb = blockIdx.x; tb < nTiles; tb += gridDim.x) {
        const long long gBase = (long long)tb * 2048;
        const int row = tb * 256 + t;

        // pred for own row: independent, issued alongside staging
        float4 p = make_float4(0.f, 0.f, 1.f, 1.f);
        if (row < B) p = pred4[row];

        if (tb * 256 + 256 <= B) {
            // full tile: async DMA staging, no VGPR round-trip
            #pragma unroll
            for (int i = 0; i < 8; ++i) {
                int j   = i * 256 + wid * 64 + lane;
                int src = (j & ~7) | ((j & 7) ^ ((j >> 3) & 7));
                __builtin_amdgcn_global_load_lds(
                    (const __attribute__((address_space(1))) void*)(tru4 + gBase + src),
                    (__attribute__((address_space(3))) void*)&lds4[i * 256 + wid * 64],
                    16, 0, 0);
            }
        } else {
            // tail tile (unused when B % 256 == 0): VGPR path, swizzled ds_write
            #pragma unroll
            for (int i = 0; i < 8; ++i) {
                int gl = i * 256 + t;
                long long g = gBase + gl;
                float4 v = make_float4(0.f, 0.f, 0.f, 0.f);
                if (g < totF4) v = tru4[g];
                int r = gl >> 3, k = gl & 7;
                lds4[r * 8 + (k ^ (r & 7))] = v;
            }
        }

        __syncthreads();   // drains DMA vmcnt + lgkmcnt for the block

        float sx = 0.f, sy = 0.f, sxx = 0.f, syy = 0.f;
        #pragma unroll
        for (int k = 0; k < 8; ++k) {
            float4 v = lds4[t * 8 + (k ^ (t & 7))];
            sx  += v.x + v.z;
            sy  += v.y + v.w;
            sxx += v.x * v.x + v.z * v.z;
            syy += v.y * v.y + v.w * v.w;
        }

        __syncthreads();   // reads done before next iteration overwrites

        if (row < B) {
            float pmx = p.x, pmy = p.y;
            float pvx = p.z + KLD_EPS, pvy = p.w + KLD_EPS;

            float tmx = sx * (1.0f / 16.0f);
            float tmy = sy * (1.0f / 16.0f);
            float tvx = (sxx - 16.0f * tmx * tmx) * (1.0f / 15.0f) + KLD_EPS;
            float tvy = (syy - 16.0f * tmy * tmy) * (1.0f / 15.0f) + KLD_EPS;

            float dx = pmx - tmx, dy = pmy - tmy;
            local += 0.5f * ( __logf(pvx / tvx) + tvx / pvx + dx * dx / pvx
                            + __logf(pvy / tvy) + tvy / pvy + dy * dy / pvy
                            - 2.0f );
        }
    }

    // deterministic block reduction (scratch aliases lds4; loop is done)
    #pragma unroll
    for (int off = 32; off > 0; off >>= 1)
        local += __shfl_down(local, off);
    __syncthreads();                 // all tile reads complete before aliasing
    if (lane == 0) ((float*)lds4)[wid] = local;
    __syncthreads();
    if (t == 0) {
        const float* smf = (const float*)lds4;
        partial[blockIdx.x] = (smf[0] + smf[1]) + (smf[2] + smf[3]);
    }
}

// Stage 2: single block sums per-block partials in fixed order, scales by 1/B.
__global__ __launch_bounds__(256) void gaze_kld_final(
    const float* __restrict__ partial, int n,
    float* __restrict__ out, float invB)
{
    const int t = threadIdx.x;
    float s = 0.0f;
    for (int i = t; i < n; i += blockDim.x) s += partial[i];

    __shared__ float sm[4];
    #pragma unroll
    for (int off = 32; off > 0; off >>= 1)
        s += __shfl_down(s, off);
    if ((t & 63) == 0) sm[t >> 6] = s;
    __syncthreads();
    if (t == 0)
        out[0] = ((sm[0] + sm[1]) + (sm[2] + sm[3])) * invB;
}

extern "C" void kernel_launch(void* const* d_in, const int* in_sizes, int n_in,
                              void* d_out, int out_size, void* d_ws, size_t ws_size,
                              hipStream_t stream) {
    const float* pred = (const float*)d_in[0];
    const float* tru  = (const float*)d_in[1];
    float* out = (float*)d_out;

    const int B = in_sizes[0] / 4;          // pred is (B,4)
    const int nTiles = (B + 255) / 256;

    int blocks = 1280;                      // exactly 5 blocks/CU at 32 KiB LDS
    if (blocks > nTiles) blocks = nTiles;
    size_t maxBlocks = ws_size / sizeof(float);
    if ((size_t)blocks > maxBlocks) blocks = (int)maxBlocks;
    if (blocks < 1) blocks = 1;

    float* partials = (float*)d_ws;

    gaze_kld_partial<<<blocks, 256, 0, stream>>>(pred, tru, partials, B, nTiles);
    gaze_kld_final<<<1, 256, 0, stream>>>(partials, blocks, out, 1.0f / (float)B);
}

// Round 9
// 30.722 us; speedup vs baseline: 2.3724x; 1.0187x over previous
//
#include <hip/hip_runtime.h>

#define KLD_EPS 1e-6f

// FINAL (measured best, 30.69us): two-kernel, grid-stride, barriered.
// Stage 1: coalesced global -> XOR-swizzled LDS -> per-thread row compute.
// Tile = 256 rows x 8 float4 (32 KiB). Element (r,k) stored at
// lds4[r*8 + (k ^ (r&7))]; writes from linear loads stay conflict-free,
// per-row reads use offset k ^ (t&7) to hit all 8 bank-groups.
// Row sums are permutation-invariant, so no un-swizzle is needed.
// 1024 blocks = 4 blocks/CU co-resident; measured ~5.7 TB/s (~90% of the
// 6.3 TB/s achievable read BW). DMA staging / more occupancy / fewer
// barriers / one-tile-per-block all measured neutral-to-worse (R4-R8).
__global__ __launch_bounds__(256) void gaze_kld_partial(
    const float* __restrict__ pred,
    const float* __restrict__ tru,
    float* __restrict__ partial,
    int B, int nTiles)
{
    __shared__ float4 lds4[2048];   // 32 KiB

    const int t = threadIdx.x;
    const float4* __restrict__ tru4  = (const float4*)tru;   // 8 float4 per row
    const float4* __restrict__ pred4 = (const float4*)pred;  // 1 float4 per row

    float local = 0.0f;
    const long long totF4 = (long long)B * 8;

    for (int tb = blockIdx.x; tb < nTiles; tb += gridDim.x) {
        const long long gBase = (long long)tb * 2048;

        // ---- coalesced global -> swizzled LDS ----
        #pragma unroll
        for (int i = 0; i < 8; ++i) {
            int gl = i * 256 + t;            // local float4 idx within tile
            long long g = gBase + gl;
            float4 v = make_float4(0.f, 0.f, 0.f, 0.f);
            if (g < totF4) v = tru4[g];
            int r = gl >> 3;                 // local row
            int k = gl & 7;
            lds4[r * 8 + (k ^ (r & 7))] = v;
        }

        // pred for own row (independent, issued alongside)
        const int row = tb * 256 + t;
        float4 p = make_float4(0.f, 0.f, 1.f, 1.f);
        if (row < B) p = pred4[row];

        __syncthreads();

        // ---- per-thread row read from LDS ----
        float sx = 0.f, sy = 0.f, sxx = 0.f, syy = 0.f;
        #pragma unroll
        for (int k = 0; k < 8; ++k) {
            float4 v = lds4[t * 8 + (k ^ (t & 7))];
            sx  += v.x + v.z;
            sy  += v.y + v.w;
            sxx += v.x * v.x + v.z * v.z;
            syy += v.y * v.y + v.w * v.w;
        }

        __syncthreads();   // reads done before next iteration's writes

        if (row < B) {
            float pmx = p.x, pmy = p.y;
            float pvx = p.z + KLD_EPS, pvy = p.w + KLD_EPS;

            float tmx = sx * (1.0f / 16.0f);
            float tmy = sy * (1.0f / 16.0f);
            float tvx = (sxx - 16.0f * tmx * tmx) * (1.0f / 15.0f) + KLD_EPS;
            float tvy = (syy - 16.0f * tmy * tmy) * (1.0f / 15.0f) + KLD_EPS;

            float dx = pmx - tmx, dy = pmy - tmy;
            local += 0.5f * ( __logf(pvx / tvx) + tvx / pvx + dx * dx / pvx
                            + __logf(pvy / tvy) + tvy / pvy + dy * dy / pvy
                            - 2.0f );
        }
    }

    // deterministic block reduction
    __shared__ float sm[4];
    #pragma unroll
    for (int off = 32; off > 0; off >>= 1)
        local += __shfl_down(local, off);
    if ((t & 63) == 0) sm[t >> 6] = local;
    __syncthreads();
    if (t == 0)
        partial[blockIdx.x] = (sm[0] + sm[1]) + (sm[2] + sm[3]);
}

// Stage 2: single block sums per-block partials in fixed order, scales by 1/B.
__global__ __launch_bounds__(256) void gaze_kld_final(
    const float* __restrict__ partial, int n,
    float* __restrict__ out, float invB)
{
    const int t = threadIdx.x;
    float s = 0.0f;
    for (int i = t; i < n; i += blockDim.x) s += partial[i];

    __shared__ float sm[4];
    #pragma unroll
    for (int off = 32; off > 0; off >>= 1)
        s += __shfl_down(s, off);
    if ((t & 63) == 0) sm[t >> 6] = s;
    __syncthreads();
    if (t == 0)
        out[0] = ((sm[0] + sm[1]) + (sm[2] + sm[3])) * invB;
}

extern "C" void kernel_launch(void* const* d_in, const int* in_sizes, int n_in,
                              void* d_out, int out_size, void* d_ws, size_t ws_size,
                              hipStream_t stream) {
    const float* pred = (const float*)d_in[0];
    const float* tru  = (const float*)d_in[1];
    float* out = (float*)d_out;

    const int B = in_sizes[0] / 4;         // pred is (B,4)
    const int nTiles = (B + 255) / 256;

    int blocks = 1024;                     // 4 blocks/CU co-resident (32 KiB LDS each)
    if (blocks > nTiles) blocks = nTiles;
    size_t maxBlocks = ws_size / sizeof(float);
    if ((size_t)blocks > maxBlocks) blocks = (int)maxBlocks;
    if (blocks < 1) blocks = 1;

    float* partials = (float*)d_ws;

    gaze_kld_partial<<<blocks, 256, 0, stream>>>(pred, tru, partials, B, nTiles);
    gaze_kld_final<<<1, 256, 0, stream>>>(partials, blocks, out, 1.0f / (float)B);
}